// Round 4
// baseline (15076.057 us; speedup 1.0000x reference)
//
#include <hip/hip_runtime.h>
#include <hip/hip_bf16.h>

#define N_SAMP 1024
#define HID 512
#define NS 9
#define IDIM 128
#define TSTEPS 64
#define KOBS 512
#define LOGTAU_STEP 1.1512925465f  // 0.5*ln(10)

// ---------------- prep: gather h rows, copy X into xi/sig_in, compute decay, update last_t
__global__ void prep_k(const float* __restrict__ obs_times, const int* __restrict__ idx,
                       const float* __restrict__ Xt, const float* __restrict__ h,
                       float* __restrict__ last_t, float* __restrict__ xi,
                       float* __restrict__ sig_in, float* __restrict__ decay, int t) {
    const int k = blockIdx.x;
    const int tid = threadIdx.x;  // 128 threads
    const int i = idx[k];
    float x = Xt[k * IDIM + tid];
    xi[k * 640 + tid] = x;
    sig_in[k * 640 + tid] = x;
    #pragma unroll
    for (int j = tid; j < HID; j += 128) xi[k * 640 + IDIM + j] = h[(size_t)i * HID + j];
    if (tid == 0) {
        float tv = obs_times[t];
        float interval = tv - last_t[i];
        last_t[i] = tv;
        #pragma unroll
        for (int s = 0; s < NS; ++s) {
            float tau = __expf(s * LOGTAU_STEP);
            decay[k * NS + s] = __expf(-interval / tau);
        }
    }
}

// ---------------- generic fp32 tiled GEMM. EPI: 0 none, 1 relu, 2 tanh, 3 loss-reduce (no C write)
template <int BM, int BN, int BK, int TM, int TN, int EPI>
__launch_bounds__(256)
__global__ void gemm_k(const float* __restrict__ A, int lda,
                       const float* __restrict__ B, int ldb,
                       const float* __restrict__ bias,
                       float* __restrict__ C, int ldc, int Kdim,
                       int colsplit, const float* __restrict__ B2,
                       const float* __restrict__ bias2,
                       const float* __restrict__ Xt, const float* __restrict__ Mt,
                       float* __restrict__ acc) {
    constexpr int THREADS = (BM / TM) * (BN / TN);
    static_assert(THREADS == 256, "need 256 threads");
    __shared__ float As[BK][BM + 4];
    __shared__ float Bs[BK][BN + 4];
    const int tid = threadIdx.x;
    const int tx = tid % (BN / TN);
    const int ty = tid / (BN / TN);
    const int m0 = blockIdx.y * BM;
    const int n0 = blockIdx.x * BN;
    const float* Bp = B;
    const float* biasp = bias;
    int nb0 = n0;
    if (colsplit > 0 && n0 >= colsplit) { Bp = B2; biasp = bias2; nb0 = n0 - colsplit; }

    float accr[TM][TN];
    #pragma unroll
    for (int i = 0; i < TM; ++i)
        #pragma unroll
        for (int j = 0; j < TN; ++j) accr[i][j] = 0.f;

    constexpr int AV = BM * BK / (THREADS * 4);
    constexpr int BV = BN * BK / (THREADS * 4);

    for (int k0 = 0; k0 < Kdim; k0 += BK) {
        #pragma unroll
        for (int v = 0; v < AV; ++v) {
            int f = tid + v * THREADS;
            int row = f / (BK / 4);
            int c4 = (f % (BK / 4)) * 4;
            float4 d = *reinterpret_cast<const float4*>(&A[(size_t)(m0 + row) * lda + k0 + c4]);
            As[c4 + 0][row] = d.x;
            As[c4 + 1][row] = d.y;
            As[c4 + 2][row] = d.z;
            As[c4 + 3][row] = d.w;
        }
        #pragma unroll
        for (int v = 0; v < BV; ++v) {
            int f = tid + v * THREADS;
            int row = f / (BN / 4);
            int c4 = (f % (BN / 4)) * 4;
            *reinterpret_cast<float4*>(&Bs[row][c4]) =
                *reinterpret_cast<const float4*>(&Bp[(size_t)(k0 + row) * ldb + nb0 + c4]);
        }
        __syncthreads();
        #pragma unroll
        for (int kk = 0; kk < BK; ++kk) {
            float a[TM], b[TN];
            #pragma unroll
            for (int i = 0; i < TM; ++i) a[i] = As[kk][ty * TM + i];
            #pragma unroll
            for (int j = 0; j < TN; ++j) b[j] = Bs[kk][tx * TN + j];
            #pragma unroll
            for (int i = 0; i < TM; ++i)
                #pragma unroll
                for (int j = 0; j < TN; ++j) accr[i][j] += a[i] * b[j];
        }
        __syncthreads();
    }

    const int row0 = m0 + ty * TM;
    const int col0 = n0 + tx * TN;
    if constexpr (EPI == 3) {
        float lsum = 0.f, msum = 0.f;
        #pragma unroll
        for (int i = 0; i < TM; ++i)
            #pragma unroll
            for (int j = 0; j < TN; ++j) {
                float p = accr[i][j] + biasp[col0 - n0 + nb0 + j];
                float x = Xt[(size_t)(row0 + i) * IDIM + col0 + j];
                float mm = Mt[(size_t)(row0 + i) * IDIM + col0 + j];
                lsum += fabsf(x - p) * mm;
                msum += mm;
            }
        float* red = &As[0][0];  // reuse LDS (>=512 floats)
        red[tid] = lsum;
        red[256 + tid] = msum;
        __syncthreads();
        #pragma unroll
        for (int s = 128; s > 0; s >>= 1) {
            if (tid < s) { red[tid] += red[tid + s]; red[256 + tid] += red[256 + tid + s]; }
            __syncthreads();
        }
        if (tid == 0) { atomicAdd(acc, red[0]); atomicAdd(acc + 1, red[256]); }
    } else {
        #pragma unroll
        for (int i = 0; i < TM; ++i)
            #pragma unroll
            for (int j = 0; j < TN; ++j) {
                float v = accr[i][j] + biasp[col0 - n0 + nb0 + j];
                if constexpr (EPI == 1) v = fmaxf(v, 0.f);
                if constexpr (EPI == 2) v = tanhf(v);
                C[(size_t)(row0 + i) * ldc + col0 + j] = v;
            }
    }
}

// ---------------- retrieval: r = softmax(-(R-logtau)^2), s = sum_s r*hh  -> sig_in[:,128:]
__global__ void retrieval_k(const float* __restrict__ RZ, const float* __restrict__ h_hat,
                            const int* __restrict__ idx, float* __restrict__ sig_in) {
    int g = blockIdx.x * blockDim.x + threadIdx.x;
    int k = g >> 9;
    int hh = g & (HID - 1);
    int i = idx[k];
    const float* Rrow = RZ + (size_t)k * 9216 + hh * NS;
    float v[NS];
    float mx = -1e30f;
    #pragma unroll
    for (int s = 0; s < NS; ++s) {
        float d = Rrow[s] - s * LOGTAU_STEP;
        v[s] = -d * d;
        mx = fmaxf(mx, v[s]);
    }
    float sum = 0.f;
    #pragma unroll
    for (int s = 0; s < NS; ++s) { v[s] = __expf(v[s] - mx); sum += v[s]; }
    const float* hp = h_hat + ((size_t)i * HID + hh) * NS;
    float sv = 0.f;
    #pragma unroll
    for (int s = 0; s < NS; ++s) sv += v[s] * hp[s];
    sig_in[k * 640 + IDIM + hh] = sv / sum;
}

// ---------------- update: z softmax, new_hh = ((1-z)hh + z*h_tilde)*decay, scatter; h = sum_s hh_pre
__global__ void update_k(const float* __restrict__ RZ, float* __restrict__ h_hat,
                         const int* __restrict__ idx, const float* __restrict__ h_tilde,
                         const float* __restrict__ decay, float* __restrict__ h) {
    int g = blockIdx.x * blockDim.x + threadIdx.x;
    int k = g >> 9;
    int hh = g & (HID - 1);
    int i = idx[k];
    const float* Zrow = RZ + (size_t)k * 9216 + 4608 + hh * NS;
    float v[NS];
    float mx = -1e30f;
    #pragma unroll
    for (int s = 0; s < NS; ++s) {
        float d = Zrow[s] - s * LOGTAU_STEP;
        v[s] = -d * d;
        mx = fmaxf(mx, v[s]);
    }
    float sum = 0.f;
    #pragma unroll
    for (int s = 0; s < NS; ++s) { v[s] = __expf(v[s] - mx); sum += v[s]; }
    float inv = 1.f / sum;
    float ht = h_tilde[(size_t)k * HID + hh];
    const float* dk = decay + k * NS;
    float* hp = h_hat + ((size_t)i * HID + hh) * NS;
    float hsum = 0.f;
    #pragma unroll
    for (int s = 0; s < NS; ++s) {
        float old = hp[s];
        hsum += old;
        float z = v[s] * inv;
        hp[s] = ((1.f - z) * old + z * ht) * dk[s];
    }
    h[(size_t)i * HID + hh] = hsum;
}

__global__ void finalize_k(const float* __restrict__ acc, float* __restrict__ out) {
    out[0] = acc[0];
    out[1] = acc[0] / acc[1];
}

extern "C" void kernel_launch(void* const* d_in, const int* in_sizes, int n_in,
                              void* d_out, int out_size, void* d_ws, size_t ws_size,
                              hipStream_t stream) {
    const float* obs_times = (const float*)d_in[0];
    const int* batch_idx = (const int*)d_in[1];
    const float* X = (const float*)d_in[2];
    const float* M = (const float*)d_in[3];
    const float* W_r = (const float*)d_in[4];
    const float* b_r = (const float*)d_in[5];
    const float* W_sig = (const float*)d_in[6];
    const float* b_sig = (const float*)d_in[7];
    const float* W_st = (const float*)d_in[8];
    const float* b_st = (const float*)d_in[9];
    const float* Wp1 = (const float*)d_in[10];
    const float* bp1 = (const float*)d_in[11];
    const float* Wp2 = (const float*)d_in[12];
    const float* bp2 = (const float*)d_in[13];

    float* p = (float*)d_ws;
    float* h_hat = p;   p += (size_t)N_SAMP * HID * NS;   // 4,718,592
    float* h = p;       p += (size_t)N_SAMP * HID;        // 524,288
    float* last_t = p;  p += N_SAMP;                      // 1,024
    float* acc = p;     p += 8;                           // loss, mobs (+pad)
    size_t zero_floats = (size_t)(p - (float*)d_ws);
    float* xi = p;      p += (size_t)KOBS * 640;
    float* sig_in = p;  p += (size_t)KOBS * 640;
    float* decay = p;   p += (size_t)KOBS * NS;
    float* P1 = p;      p += (size_t)KOBS * HID;
    float* RZ = p;      p += (size_t)KOBS * 9216;
    float* h_tilde = p; p += (size_t)KOBS * HID;

    hipMemsetAsync(d_ws, 0, zero_floats * sizeof(float), stream);

    for (int t = 0; t < TSTEPS; ++t) {
        const int* idx_t = batch_idx + (size_t)t * KOBS;
        const float* Xt = X + (size_t)t * KOBS * IDIM;
        const float* Mt = M + (size_t)t * KOBS * IDIM;

        prep_k<<<KOBS, 128, 0, stream>>>(obs_times, idx_t, Xt, h, last_t, xi, sig_in, decay, t);

        // P1 = relu(h_i @ Wp1 + bp1)   [512,512] , K=512, A = xi[:,128:]
        gemm_k<64, 64, 16, 4, 4, 1><<<dim3(8, 8), 256, 0, stream>>>(
            xi + IDIM, 640, Wp1, HID, bp1, P1, HID, HID, 0, nullptr, nullptr,
            nullptr, nullptr, nullptr);

        // p = P1 @ Wp2 + bp2 -> loss reduce   [512,128], K=512
        gemm_k<64, 64, 16, 4, 4, 3><<<dim3(2, 8), 256, 0, stream>>>(
            P1, HID, Wp2, IDIM, bp2, nullptr, 0, HID, 0, nullptr, nullptr,
            Xt, Mt, acc);

        // RZ = xi @ [W_r | W_st] + [b_r | b_st]   [512, 9216], K=640
        gemm_k<128, 128, 16, 8, 8, 0><<<dim3(72, 4), 256, 0, stream>>>(
            xi, 640, W_r, 4608, b_r, RZ, 9216, 640, 4608, W_st, b_st,
            nullptr, nullptr, nullptr);

        // retrieval softmax + weighted hh sum -> sig_in[:,128:]
        retrieval_k<<<(KOBS * HID) / 256, 256, 0, stream>>>(RZ, h_hat, idx_t, sig_in);

        // h_tilde = tanh(sig_in @ W_sig + b_sig)   [512,512], K=640
        gemm_k<64, 64, 16, 4, 4, 2><<<dim3(8, 8), 256, 0, stream>>>(
            sig_in, 640, W_sig, HID, b_sig, h_tilde, HID, 640, 0, nullptr, nullptr,
            nullptr, nullptr, nullptr);

        // z softmax, state update + scatters
        update_k<<<(KOBS * HID) / 256, 256, 0, stream>>>(RZ, h_hat, idx_t, h_tilde, decay, h);
    }

    finalize_k<<<1, 1, 0, stream>>>(acc, (float*)d_out);
}

// Round 11
// 9320.654 us; speedup vs baseline: 1.6175x; 1.6175x over previous
//
#include <hip/hip_runtime.h>
#include <hip/hip_bf16.h>

#define N_SAMP 1024
#define HID 512
#define NS 9
#define IDIM 128
#define TSTEPS 64
#define KOBS 512
#define LOGTAU_STEP 1.1512925465f  // 0.5*ln(10)

typedef __attribute__((ext_vector_type(8))) short bf16x8;
typedef __attribute__((ext_vector_type(4))) float f32x4;

__device__ inline unsigned short f2bf(float f) {
    unsigned int u = __float_as_uint(f);
    unsigned int r = (u + 0x7FFFu + ((u >> 16) & 1u)) >> 16;  // RNE
    return (unsigned short)r;
}

// ---------------- prep: gather h rows, build xi (f32 + bf16), sig_in[:,:128], decay, last_t
__global__ void prep_k(const float* __restrict__ obs_times, const int* __restrict__ idx,
                       const float* __restrict__ Xt, const float* __restrict__ h,
                       float* __restrict__ last_t, float* __restrict__ xi,
                       unsigned short* __restrict__ xi_bf,
                       float* __restrict__ sig_in, float* __restrict__ decay, int t) {
    const int k = blockIdx.x;
    const int tid = threadIdx.x;  // 128 threads
    const int i = idx[k];
    float x = Xt[k * IDIM + tid];
    xi[k * 640 + tid] = x;
    xi_bf[k * 640 + tid] = f2bf(x);
    sig_in[k * 640 + tid] = x;
    #pragma unroll
    for (int j = tid; j < HID; j += 128) {
        float hv = h[(size_t)i * HID + j];
        xi[k * 640 + IDIM + j] = hv;
        xi_bf[k * 640 + IDIM + j] = f2bf(hv);
    }
    if (tid == 0) {
        float tv = obs_times[t];
        float interval = tv - last_t[i];
        last_t[i] = tv;
        #pragma unroll
        for (int s = 0; s < NS; ++s) {
            float tau = __expf(s * LOGTAU_STEP);
            decay[k * NS + s] = __expf(-interval / tau);
        }
    }
}

// ---------------- one-time: Wt[n][k] = bf16(W(k,n)) for combined [W_r|W_st]; bias_all = [b_r|b_st]
__global__ void convw_k(const float* __restrict__ W_r, const float* __restrict__ W_st,
                        const float* __restrict__ b_r, const float* __restrict__ b_st,
                        unsigned short* __restrict__ Bt, float* __restrict__ bias) {
    size_t g = (size_t)blockIdx.x * 256 + threadIdx.x;  // 9216*640 total, n fastest
    int n = (int)(g % 9216);
    int k = (int)(g / 9216);
    float v = (n < 4608) ? W_r[(size_t)k * 4608 + n] : W_st[(size_t)k * 4608 + (n - 4608)];
    Bt[(size_t)n * 640 + k] = f2bf(v);
    if (g < 9216) bias[g] = (g < 4608) ? b_r[g] : b_st[g - 4608];
}

// ---------------- bf16 MFMA GEMM: C[512][9216] = Abf[512][640] x Bt[9216][640]^T + bias
// 64x128 tile, BK=64, 4 waves (2x2), padded LDS, 16x16x32 bf16 MFMA
#define GBM 64
#define GBN 128
#define GBK 64
#define LDP 72  // padded row length in bf16 elems (64 + 8)

__launch_bounds__(256, 2)
__global__ void mfma_gemm_k(const unsigned short* __restrict__ Abf,
                            const unsigned short* __restrict__ Bt,
                            const float* __restrict__ bias,
                            float* __restrict__ C) {
    __shared__ unsigned short As[GBM][LDP];  //  9216 B
    __shared__ unsigned short Bs[GBN][LDP];  // 18432 B
    const int tid = threadIdx.x;
    const int wave = tid >> 6;
    const int lane = tid & 63;
    const int wr = wave >> 1;   // 0..1 : 32-row slab
    const int wc = wave & 1;    // 0..1 : 64-col slab
    const int m0 = blockIdx.y * GBM;
    const int n0 = blockIdx.x * GBN;
    const int lrow = lane & 15;
    const int lk8 = (lane >> 4) * 8;

    f32x4 acc[2][4];
    #pragma unroll
    for (int m = 0; m < 2; ++m)
        #pragma unroll
        for (int n = 0; n < 4; ++n) acc[m][n] = (f32x4){0.f, 0.f, 0.f, 0.f};

    for (int k0 = 0; k0 < 640; k0 += GBK) {
        // stage A: 64 rows x 64 k (16B chunks, 512 total)
        #pragma unroll
        for (int c = tid; c < 512; c += 256) {
            int row = c >> 3, kq = c & 7;
            const float4 d = *reinterpret_cast<const float4*>(
                Abf + (size_t)(m0 + row) * 640 + k0 + kq * 8);
            *reinterpret_cast<float4*>(&As[row][kq * 8]) = d;
        }
        // stage B: 128 rows(cols of C) x 64 k (1024 chunks)
        #pragma unroll
        for (int c = tid; c < 1024; c += 256) {
            int row = c >> 3, kq = c & 7;
            const float4 d = *reinterpret_cast<const float4*>(
                Bt + (size_t)(n0 + row) * 640 + k0 + kq * 8);
            *reinterpret_cast<float4*>(&Bs[row][kq * 8]) = d;
        }
        __syncthreads();
        #pragma unroll
        for (int kk = 0; kk < 2; ++kk) {
            bf16x8 a[2], b[4];
            #pragma unroll
            for (int m = 0; m < 2; ++m)
                a[m] = *reinterpret_cast<const bf16x8*>(&As[wr * 32 + m * 16 + lrow][kk * 32 + lk8]);
            #pragma unroll
            for (int n = 0; n < 4; ++n)
                b[n] = *reinterpret_cast<const bf16x8*>(&Bs[wc * 64 + n * 16 + lrow][kk * 32 + lk8]);
            #pragma unroll
            for (int m = 0; m < 2; ++m)
                #pragma unroll
                for (int n = 0; n < 4; ++n)
                    acc[m][n] = __builtin_amdgcn_mfma_f32_16x16x32_bf16(a[m], b[n], acc[m][n], 0, 0, 0);
        }
        __syncthreads();
    }

    // epilogue: C/D layout col=lane&15, row=(lane>>4)*4+reg  [m89/m91 verified]
    const int rg4 = (lane >> 4) * 4;
    #pragma unroll
    for (int n = 0; n < 4; ++n) {
        int gc = n0 + wc * 64 + n * 16 + lrow;
        float bv = bias[gc];
        #pragma unroll
        for (int m = 0; m < 2; ++m) {
            int gr0 = m0 + wr * 32 + m * 16 + rg4;
            #pragma unroll
            for (int j = 0; j < 4; ++j)
                C[(size_t)(gr0 + j) * 9216 + gc] = acc[m][n][j] + bv;
        }
    }
}

// ---------------- generic fp32 tiled GEMM. EPI: 0 none, 1 relu, 2 tanh, 3 loss-reduce
template <int BM, int BN, int BK, int TM, int TN, int EPI>
__launch_bounds__(256)
__global__ void gemm_k(const float* __restrict__ A, int lda,
                       const float* __restrict__ B, int ldb,
                       const float* __restrict__ bias,
                       float* __restrict__ C, int ldc, int Kdim,
                       const float* __restrict__ Xt, const float* __restrict__ Mt,
                       float* __restrict__ acc) {
    constexpr int THREADS = (BM / TM) * (BN / TN);
    static_assert(THREADS == 256, "need 256 threads");
    __shared__ float As[BK][BM + 4];
    __shared__ float Bs[BK][BN + 4];
    const int tid = threadIdx.x;
    const int tx = tid % (BN / TN);
    const int ty = tid / (BN / TN);
    const int m0 = blockIdx.y * BM;
    const int n0 = blockIdx.x * BN;

    float accr[TM][TN];
    #pragma unroll
    for (int i = 0; i < TM; ++i)
        #pragma unroll
        for (int j = 0; j < TN; ++j) accr[i][j] = 0.f;

    constexpr int AV = BM * BK / (THREADS * 4);
    constexpr int BV = BN * BK / (THREADS * 4);

    for (int k0 = 0; k0 < Kdim; k0 += BK) {
        #pragma unroll
        for (int v = 0; v < AV; ++v) {
            int f = tid + v * THREADS;
            int row = f / (BK / 4);
            int c4 = (f % (BK / 4)) * 4;
            float4 d = *reinterpret_cast<const float4*>(&A[(size_t)(m0 + row) * lda + k0 + c4]);
            As[c4 + 0][row] = d.x;
            As[c4 + 1][row] = d.y;
            As[c4 + 2][row] = d.z;
            As[c4 + 3][row] = d.w;
        }
        #pragma unroll
        for (int v = 0; v < BV; ++v) {
            int f = tid + v * THREADS;
            int row = f / (BN / 4);
            int c4 = (f % (BN / 4)) * 4;
            *reinterpret_cast<float4*>(&Bs[row][c4]) =
                *reinterpret_cast<const float4*>(&B[(size_t)(k0 + row) * ldb + n0 + c4]);
        }
        __syncthreads();
        #pragma unroll
        for (int kk = 0; kk < BK; ++kk) {
            float a[TM], b[TN];
            #pragma unroll
            for (int i = 0; i < TM; ++i) a[i] = As[kk][ty * TM + i];
            #pragma unroll
            for (int j = 0; j < TN; ++j) b[j] = Bs[kk][tx * TN + j];
            #pragma unroll
            for (int i = 0; i < TM; ++i)
                #pragma unroll
                for (int j = 0; j < TN; ++j) accr[i][j] += a[i] * b[j];
        }
        __syncthreads();
    }

    const int row0 = m0 + ty * TM;
    const int col0 = n0 + tx * TN;
    if constexpr (EPI == 3) {
        float lsum = 0.f, msum = 0.f;
        #pragma unroll
        for (int i = 0; i < TM; ++i)
            #pragma unroll
            for (int j = 0; j < TN; ++j) {
                float p = accr[i][j] + bias[col0 + j];
                float x = Xt[(size_t)(row0 + i) * IDIM + col0 + j];
                float mm = Mt[(size_t)(row0 + i) * IDIM + col0 + j];
                lsum += fabsf(x - p) * mm;
                msum += mm;
            }
        float* red = &As[0][0];
        red[tid] = lsum;
        red[256 + tid] = msum;
        __syncthreads();
        #pragma unroll
        for (int s = 128; s > 0; s >>= 1) {
            if (tid < s) { red[tid] += red[tid + s]; red[256 + tid] += red[256 + tid + s]; }
            __syncthreads();
        }
        if (tid == 0) { atomicAdd(acc, red[0]); atomicAdd(acc + 1, red[256]); }
    } else {
        #pragma unroll
        for (int i = 0; i < TM; ++i)
            #pragma unroll
            for (int j = 0; j < TN; ++j) {
                float v = accr[i][j] + bias[col0 + j];
                if constexpr (EPI == 1) v = fmaxf(v, 0.f);
                if constexpr (EPI == 2) v = tanhf(v);
                C[(size_t)(row0 + i) * ldc + col0 + j] = v;
            }
    }
}

// ---------------- retrieval: r = softmax(-(R-logtau)^2), s = sum_s r*hh  -> sig_in[:,128:]
__global__ void retrieval_k(const float* __restrict__ RZ, const float* __restrict__ h_hat,
                            const int* __restrict__ idx, float* __restrict__ sig_in) {
    int g = blockIdx.x * blockDim.x + threadIdx.x;
    int k = g >> 9;
    int hh = g & (HID - 1);
    int i = idx[k];
    const float* Rrow = RZ + (size_t)k * 9216 + hh * NS;
    float v[NS];
    float mx = -1e30f;
    #pragma unroll
    for (int s = 0; s < NS; ++s) {
        float d = Rrow[s] - s * LOGTAU_STEP;
        v[s] = -d * d;
        mx = fmaxf(mx, v[s]);
    }
    float sum = 0.f;
    #pragma unroll
    for (int s = 0; s < NS; ++s) { v[s] = __expf(v[s] - mx); sum += v[s]; }
    const float* hp = h_hat + ((size_t)i * HID + hh) * NS;
    float sv = 0.f;
    #pragma unroll
    for (int s = 0; s < NS; ++s) sv += v[s] * hp[s];
    sig_in[k * 640 + IDIM + hh] = sv / sum;
}

// ---------------- update: z softmax, new_hh = ((1-z)hh + z*h_tilde)*decay, scatter
__global__ void update_k(const float* __restrict__ RZ, float* __restrict__ h_hat,
                         const int* __restrict__ idx, const float* __restrict__ h_tilde,
                         const float* __restrict__ decay, float* __restrict__ h) {
    int g = blockIdx.x * blockDim.x + threadIdx.x;
    int k = g >> 9;
    int hh = g & (HID - 1);
    int i = idx[k];
    const float* Zrow = RZ + (size_t)k * 9216 + 4608 + hh * NS;
    float v[NS];
    float mx = -1e30f;
    #pragma unroll
    for (int s = 0; s < NS; ++s) {
        float d = Zrow[s] - s * LOGTAU_STEP;
        v[s] = -d * d;
        mx = fmaxf(mx, v[s]);
    }
    float sum = 0.f;
    #pragma unroll
    for (int s = 0; s < NS; ++s) { v[s] = __expf(v[s] - mx); sum += v[s]; }
    float inv = 1.f / sum;
    float ht = h_tilde[(size_t)k * HID + hh];
    const float* dk = decay + k * NS;
    float* hp = h_hat + ((size_t)i * HID + hh) * NS;
    float hsum = 0.f;
    #pragma unroll
    for (int s = 0; s < NS; ++s) {
        float old = hp[s];
        hsum += old;
        float z = v[s] * inv;
        hp[s] = ((1.f - z) * old + z * ht) * dk[s];
    }
    h[(size_t)i * HID + hh] = hsum;
}

__global__ void finalize_k(const float* __restrict__ acc, float* __restrict__ out) {
    out[0] = acc[0];
    out[1] = acc[0] / acc[1];
}

extern "C" void kernel_launch(void* const* d_in, const int* in_sizes, int n_in,
                              void* d_out, int out_size, void* d_ws, size_t ws_size,
                              hipStream_t stream) {
    const float* obs_times = (const float*)d_in[0];
    const int* batch_idx = (const int*)d_in[1];
    const float* X = (const float*)d_in[2];
    const float* M = (const float*)d_in[3];
    const float* W_r = (const float*)d_in[4];
    const float* b_r = (const float*)d_in[5];
    const float* W_sig = (const float*)d_in[6];
    const float* b_sig = (const float*)d_in[7];
    const float* W_st = (const float*)d_in[8];
    const float* b_st = (const float*)d_in[9];
    const float* Wp1 = (const float*)d_in[10];
    const float* bp1 = (const float*)d_in[11];
    const float* Wp2 = (const float*)d_in[12];
    const float* bp2 = (const float*)d_in[13];

    float* p = (float*)d_ws;
    float* h_hat = p;   p += (size_t)N_SAMP * HID * NS;   // zeroed
    float* h = p;       p += (size_t)N_SAMP * HID;        // zeroed
    float* last_t = p;  p += N_SAMP;                      // zeroed
    float* acc = p;     p += 8;                           // zeroed
    size_t zero_floats = (size_t)(p - (float*)d_ws);
    float* xi = p;      p += (size_t)KOBS * 640;
    float* sig_in = p;  p += (size_t)KOBS * 640;
    float* decay = p;   p += (size_t)KOBS * NS + 7;
    float* P1 = p;      p += (size_t)KOBS * HID;
    float* RZ = p;      p += (size_t)KOBS * 9216;
    float* h_tilde = p; p += (size_t)KOBS * HID;
    float* bias_all = p; p += 9216;
    unsigned short* xi_bf = (unsigned short*)p;  // 512*640 ushort
    unsigned short* Wt = xi_bf + (size_t)KOBS * 640;  // 9216*640 ushort

    hipMemsetAsync(d_ws, 0, zero_floats * sizeof(float), stream);

    // one-time weight conversion: Wt[9216][640] bf16 (transposed), bias_all[9216]
    convw_k<<<23040, 256, 0, stream>>>(W_r, W_st, b_r, b_st, Wt, bias_all);

    for (int t = 0; t < TSTEPS; ++t) {
        const int* idx_t = batch_idx + (size_t)t * KOBS;
        const float* Xt = X + (size_t)t * KOBS * IDIM;
        const float* Mt = M + (size_t)t * KOBS * IDIM;

        prep_k<<<KOBS, 128, 0, stream>>>(obs_times, idx_t, Xt, h, last_t, xi, xi_bf, sig_in, decay, t);

        // P1 = relu(h_i @ Wp1 + bp1)   [512,512], K=512
        gemm_k<64, 64, 16, 4, 4, 1><<<dim3(8, 8), 256, 0, stream>>>(
            xi + IDIM, 640, Wp1, HID, bp1, P1, HID, HID, nullptr, nullptr, nullptr);

        // loss reduce from p = P1 @ Wp2 + bp2   [512,128], K=512
        gemm_k<64, 64, 16, 4, 4, 3><<<dim3(2, 8), 256, 0, stream>>>(
            P1, HID, Wp2, IDIM, bp2, nullptr, 0, HID, Xt, Mt, acc);

        // RZ = xi_bf @ Wt^T + bias_all   [512, 9216], K=640  (bf16 MFMA)
        mfma_gemm_k<<<dim3(9216 / GBN, KOBS / GBM), 256, 0, stream>>>(xi_bf, Wt, bias_all, RZ);

        // retrieval softmax + weighted hh sum -> sig_in[:,128:]
        retrieval_k<<<(KOBS * HID) / 256, 256, 0, stream>>>(RZ, h_hat, idx_t, sig_in);

        // h_tilde = tanh(sig_in @ W_sig + b_sig)   [512,512], K=640
        gemm_k<64, 64, 16, 4, 4, 2><<<dim3(8, 8), 256, 0, stream>>>(
            sig_in, 640, W_sig, HID, b_sig, h_tilde, HID, 640, nullptr, nullptr, nullptr);

        // z softmax, state update + scatters
        update_k<<<(KOBS * HID) / 256, 256, 0, stream>>>(RZ, h_hat, idx_t, h_tilde, decay, h);
    }

    finalize_k<<<1, 1, 0, stream>>>(acc, (float*)d_out);
}

// Round 15
// 7023.800 us; speedup vs baseline: 2.1464x; 1.3270x over previous
//
#include <hip/hip_runtime.h>
#include <hip/hip_bf16.h>

#define N_SAMP 1024
#define HID 512
#define NS 9
#define IDIM 128
#define TSTEPS 64
#define KOBS 512
#define LOGTAU_STEP 1.1512925465f  // 0.5*ln(10)

typedef __attribute__((ext_vector_type(8))) short bf16x8;
typedef __attribute__((ext_vector_type(4))) float f32x4;

__device__ inline unsigned short f2bf(float f) {
    unsigned int u = __float_as_uint(f);
    unsigned int r = (u + 0x7FFFu + ((u >> 16) & 1u)) >> 16;  // RNE
    return (unsigned short)r;
}

// ---------------- prep: gather h rows -> xi_bf; X -> xi_bf & sig_bf; decay, last_t
__global__ void prep_k(const float* __restrict__ obs_times, const int* __restrict__ idx,
                       const float* __restrict__ Xt, const float* __restrict__ h,
                       float* __restrict__ last_t, unsigned short* __restrict__ xi_bf,
                       unsigned short* __restrict__ sig_bf, float* __restrict__ decay, int t) {
    const int k = blockIdx.x;
    const int tid = threadIdx.x;  // 128 threads
    const int i = idx[k];
    unsigned short xb = f2bf(Xt[k * IDIM + tid]);
    xi_bf[k * 640 + tid] = xb;
    sig_bf[k * 640 + tid] = xb;
    #pragma unroll
    for (int j = tid; j < HID; j += 128)
        xi_bf[k * 640 + IDIM + j] = f2bf(h[(size_t)i * HID + j]);
    if (tid == 0) {
        float tv = obs_times[t];
        float interval = tv - last_t[i];
        last_t[i] = tv;
        #pragma unroll
        for (int s = 0; s < NS; ++s) {
            float tau = __expf(s * LOGTAU_STEP);
            decay[k * NS + s] = __expf(-interval / tau);
        }
    }
}

// ---------------- one-time: Wt[n][k] = bf16([W_r|W_st](k,n)); bias_all = [b_r|b_st]
__global__ void convw_k(const float* __restrict__ W_r, const float* __restrict__ W_st,
                        const float* __restrict__ b_r, const float* __restrict__ b_st,
                        unsigned short* __restrict__ Bt, float* __restrict__ bias) {
    size_t g = (size_t)blockIdx.x * 256 + threadIdx.x;  // 9216*640
    int n = (int)(g % 9216);
    int k = (int)(g / 9216);
    float v = (n < 4608) ? W_r[(size_t)k * 4608 + n] : W_st[(size_t)k * 4608 + (n - 4608)];
    Bt[(size_t)n * 640 + k] = f2bf(v);
    if (g < 9216) bias[g] = (g < 4608) ? b_r[g] : b_st[g - 4608];
}

// ---------------- one-time: transposed bf16 copies of Wp1 [512,512], W_sig [640,512], Wp2 [512,128]
__global__ void convw2_k(const float* __restrict__ Wp1, const float* __restrict__ W_sig,
                         const float* __restrict__ Wp2,
                         unsigned short* __restrict__ Wp1t, unsigned short* __restrict__ Wsigt,
                         unsigned short* __restrict__ Wp2t) {
    int g = blockIdx.x * 256 + threadIdx.x;
    if (g < 512 * 512) {                       // Wp1t[n][k] = Wp1[k][n]
        int n = g >> 9, k = g & 511;
        Wp1t[g] = f2bf(Wp1[(size_t)k * 512 + n]);
    } else if (g < 512 * 512 + 512 * 640) {    // Wsigt[n][k] = W_sig[k][n], n<512, k<640
        int q = g - 512 * 512;
        int n = q / 640, k = q % 640;
        Wsigt[q] = f2bf(W_sig[(size_t)k * 512 + n]);
    } else if (g < 512 * 512 + 512 * 640 + 128 * 512) {  // Wp2t[n][k] = Wp2[k][n], n<128, k<512
        int q = g - 512 * 512 - 512 * 640;
        int n = q >> 9, k = q & 511;
        Wp2t[q] = f2bf(Wp2[(size_t)k * 128 + n]);
    }
}

// ---------------- bf16 MFMA GEMM, BM=64 BN=128 BK=64, 4 waves (2x2), padded LDS.
// C[M][N] = A[M][K] x B[N][K]^T + bias.  EPI: 0 f32-out, 1 relu->bf16, 2 tanh->f32, 3 loss-reduce
#define LDP 72  // padded row length in bf16 elems (64 + 8)

template <int EPI>
__launch_bounds__(256, 2)
__global__ void mgemm_k(const unsigned short* __restrict__ Abf, int lda,
                        const unsigned short* __restrict__ Bt, int ldb,
                        const float* __restrict__ bias,
                        void* __restrict__ Cout, int ldc, int Kdim,
                        const float* __restrict__ Xt, const float* __restrict__ Mt,
                        float* __restrict__ acc) {
    __shared__ unsigned short As[64][LDP];   //  9216 B
    __shared__ unsigned short Bs[128][LDP];  // 18432 B
    const int tid = threadIdx.x;
    const int wave = tid >> 6;
    const int lane = tid & 63;
    const int wr = wave >> 1;   // 0..1 : 32-row slab
    const int wc = wave & 1;    // 0..1 : 64-col slab
    const int m0 = blockIdx.y * 64;
    const int n0 = blockIdx.x * 128;
    const int lrow = lane & 15;
    const int lk8 = (lane >> 4) * 8;

    f32x4 acr[2][4];
    #pragma unroll
    for (int m = 0; m < 2; ++m)
        #pragma unroll
        for (int n = 0; n < 4; ++n) acr[m][n] = (f32x4){0.f, 0.f, 0.f, 0.f};

    for (int k0 = 0; k0 < Kdim; k0 += 64) {
        #pragma unroll
        for (int c = tid; c < 512; c += 256) {
            int row = c >> 3, kq = c & 7;
            const float4 d = *reinterpret_cast<const float4*>(
                Abf + (size_t)(m0 + row) * lda + k0 + kq * 8);
            *reinterpret_cast<float4*>(&As[row][kq * 8]) = d;
        }
        #pragma unroll
        for (int c = tid; c < 1024; c += 256) {
            int row = c >> 3, kq = c & 7;
            const float4 d = *reinterpret_cast<const float4*>(
                Bt + (size_t)(n0 + row) * ldb + k0 + kq * 8);
            *reinterpret_cast<float4*>(&Bs[row][kq * 8]) = d;
        }
        __syncthreads();
        #pragma unroll
        for (int kk = 0; kk < 2; ++kk) {
            bf16x8 a[2], b[4];
            #pragma unroll
            for (int m = 0; m < 2; ++m)
                a[m] = *reinterpret_cast<const bf16x8*>(&As[wr * 32 + m * 16 + lrow][kk * 32 + lk8]);
            #pragma unroll
            for (int n = 0; n < 4; ++n)
                b[n] = *reinterpret_cast<const bf16x8*>(&Bs[wc * 64 + n * 16 + lrow][kk * 32 + lk8]);
            #pragma unroll
            for (int m = 0; m < 2; ++m)
                #pragma unroll
                for (int n = 0; n < 4; ++n)
                    acr[m][n] = __builtin_amdgcn_mfma_f32_16x16x32_bf16(a[m], b[n], acr[m][n], 0, 0, 0);
        }
        __syncthreads();
    }

    // C/D layout: col=lane&15, row=(lane>>4)*4+reg  [m89/m91 verified; validated on HW round 11]
    const int rg4 = (lane >> 4) * 4;
    if constexpr (EPI == 3) {
        float lsum = 0.f, msum = 0.f;
        #pragma unroll
        for (int n = 0; n < 4; ++n) {
            int gc = n0 + wc * 64 + n * 16 + lrow;
            float bv = bias[gc];
            #pragma unroll
            for (int m = 0; m < 2; ++m) {
                int gr0 = m0 + wr * 32 + m * 16 + rg4;
                #pragma unroll
                for (int j = 0; j < 4; ++j) {
                    float pv = acr[m][n][j] + bv;
                    float x = Xt[(size_t)(gr0 + j) * IDIM + gc];
                    float mm = Mt[(size_t)(gr0 + j) * IDIM + gc];
                    lsum += fabsf(x - pv) * mm;
                    msum += mm;
                }
            }
        }
        float* red = reinterpret_cast<float*>(&As[0][0]);  // 2 KiB of 9 KiB LDS
        __syncthreads();
        red[tid] = lsum;
        red[256 + tid] = msum;
        __syncthreads();
        #pragma unroll
        for (int s = 128; s > 0; s >>= 1) {
            if (tid < s) { red[tid] += red[tid + s]; red[256 + tid] += red[256 + tid + s]; }
            __syncthreads();
        }
        if (tid == 0) { atomicAdd(acc, red[0]); atomicAdd(acc + 1, red[256]); }
    } else {
        #pragma unroll
        for (int n = 0; n < 4; ++n) {
            int gc = n0 + wc * 64 + n * 16 + lrow;
            float bv = bias[gc];
            #pragma unroll
            for (int m = 0; m < 2; ++m) {
                int gr0 = m0 + wr * 32 + m * 16 + rg4;
                #pragma unroll
                for (int j = 0; j < 4; ++j) {
                    float v = acr[m][n][j] + bv;
                    if constexpr (EPI == 0) {
                        ((float*)Cout)[(size_t)(gr0 + j) * ldc + gc] = v;
                    } else if constexpr (EPI == 1) {
                        ((unsigned short*)Cout)[(size_t)(gr0 + j) * ldc + gc] = f2bf(fmaxf(v, 0.f));
                    } else {
                        ((float*)Cout)[(size_t)(gr0 + j) * ldc + gc] = tanhf(v);
                    }
                }
            }
        }
    }
}

// ---------------- retrieval: r = softmax(-(R-logtau)^2), s = sum_s r*hh  -> sig_bf[:,128:]
__global__ void retrieval_k(const float* __restrict__ RZ, const float* __restrict__ h_hat,
                            const int* __restrict__ idx, unsigned short* __restrict__ sig_bf) {
    int g = blockIdx.x * blockDim.x + threadIdx.x;
    int k = g >> 9;
    int hh = g & (HID - 1);
    int i = idx[k];
    const float* Rrow = RZ + (size_t)k * 9216 + hh * NS;
    float v[NS];
    float mx = -1e30f;
    #pragma unroll
    for (int s = 0; s < NS; ++s) {
        float d = Rrow[s] - s * LOGTAU_STEP;
        v[s] = -d * d;
        mx = fmaxf(mx, v[s]);
    }
    float sum = 0.f;
    #pragma unroll
    for (int s = 0; s < NS; ++s) { v[s] = __expf(v[s] - mx); sum += v[s]; }
    const float* hp = h_hat + ((size_t)i * HID + hh) * NS;
    float sv = 0.f;
    #pragma unroll
    for (int s = 0; s < NS; ++s) sv += v[s] * hp[s];
    sig_bf[k * 640 + IDIM + hh] = f2bf(sv / sum);
}

// ---------------- update: z softmax, new_hh = ((1-z)hh + z*h_tilde)*decay, scatter; h = sum hh_pre
__global__ void update_k(const float* __restrict__ RZ, float* __restrict__ h_hat,
                         const int* __restrict__ idx, const float* __restrict__ h_tilde,
                         const float* __restrict__ decay, float* __restrict__ h) {
    int g = blockIdx.x * blockDim.x + threadIdx.x;
    int k = g >> 9;
    int hh = g & (HID - 1);
    int i = idx[k];
    const float* Zrow = RZ + (size_t)k * 9216 + 4608 + hh * NS;
    float v[NS];
    float mx = -1e30f;
    #pragma unroll
    for (int s = 0; s < NS; ++s) {
        float d = Zrow[s] - s * LOGTAU_STEP;
        v[s] = -d * d;
        mx = fmaxf(mx, v[s]);
    }
    float sum = 0.f;
    #pragma unroll
    for (int s = 0; s < NS; ++s) { v[s] = __expf(v[s] - mx); sum += v[s]; }
    float inv = 1.f / sum;
    float ht = h_tilde[(size_t)k * HID + hh];
    const float* dk = decay + k * NS;
    float* hp = h_hat + ((size_t)i * HID + hh) * NS;
    float hsum = 0.f;
    #pragma unroll
    for (int s = 0; s < NS; ++s) {
        float old = hp[s];
        hsum += old;
        float z = v[s] * inv;
        hp[s] = ((1.f - z) * old + z * ht) * dk[s];
    }
    h[(size_t)i * HID + hh] = hsum;
}

__global__ void finalize_k(const float* __restrict__ acc, float* __restrict__ out) {
    out[0] = acc[0];
    out[1] = acc[0] / acc[1];
}

extern "C" void kernel_launch(void* const* d_in, const int* in_sizes, int n_in,
                              void* d_out, int out_size, void* d_ws, size_t ws_size,
                              hipStream_t stream) {
    const float* obs_times = (const float*)d_in[0];
    const int* batch_idx = (const int*)d_in[1];
    const float* X = (const float*)d_in[2];
    const float* M = (const float*)d_in[3];
    const float* W_r = (const float*)d_in[4];
    const float* b_r = (const float*)d_in[5];
    const float* W_sig = (const float*)d_in[6];
    const float* b_sig = (const float*)d_in[7];
    const float* W_st = (const float*)d_in[8];
    const float* b_st = (const float*)d_in[9];
    const float* Wp1 = (const float*)d_in[10];
    const float* bp1 = (const float*)d_in[11];
    const float* Wp2 = (const float*)d_in[12];
    const float* bp2 = (const float*)d_in[13];

    float* p = (float*)d_ws;
    float* h_hat = p;   p += (size_t)N_SAMP * HID * NS;   // zeroed
    float* h = p;       p += (size_t)N_SAMP * HID;        // zeroed
    float* last_t = p;  p += N_SAMP;                      // zeroed
    float* acc = p;     p += 8;                           // zeroed
    size_t zero_floats = (size_t)(p - (float*)d_ws);
    float* decay = p;    p += (size_t)KOBS * NS + 7;
    float* RZ = p;       p += (size_t)KOBS * 9216;
    float* h_tilde = p;  p += (size_t)KOBS * HID;
    float* bias_all = p; p += 9216;
    unsigned short* xi_bf  = (unsigned short*)p;
    unsigned short* sig_bf = xi_bf + (size_t)KOBS * 640;
    unsigned short* P1_bf  = sig_bf + (size_t)KOBS * 640;
    unsigned short* Wt     = P1_bf + (size_t)KOBS * HID;      // 9216*640
    unsigned short* Wp1t   = Wt + (size_t)9216 * 640;         // 512*512
    unsigned short* Wsigt  = Wp1t + (size_t)512 * 512;        // 512*640
    unsigned short* Wp2t   = Wsigt + (size_t)512 * 640;       // 128*512

    hipMemsetAsync(d_ws, 0, zero_floats * sizeof(float), stream);

    // one-time weight conversions
    convw_k<<<23040, 256, 0, stream>>>(W_r, W_st, b_r, b_st, Wt, bias_all);
    convw2_k<<<(512 * 512 + 512 * 640 + 128 * 512 + 255) / 256, 256, 0, stream>>>(
        Wp1, W_sig, Wp2, Wp1t, Wsigt, Wp2t);

    for (int t = 0; t < TSTEPS; ++t) {
        const int* idx_t = batch_idx + (size_t)t * KOBS;
        const float* Xt = X + (size_t)t * KOBS * IDIM;
        const float* Mt = M + (size_t)t * KOBS * IDIM;

        prep_k<<<KOBS, 128, 0, stream>>>(obs_times, idx_t, Xt, h, last_t, xi_bf, sig_bf, decay, t);

        // P1_bf = relu(h_i @ Wp1 + bp1) as bf16   [512,512], K=512
        mgemm_k<1><<<dim3(4, 8), 256, 0, stream>>>(
            xi_bf + IDIM, 640, Wp1t, 512, bp1, P1_bf, 512, 512, nullptr, nullptr, nullptr);

        // loss reduce from p = P1 @ Wp2 + bp2   [512,128], K=512
        mgemm_k<3><<<dim3(1, 8), 256, 0, stream>>>(
            P1_bf, 512, Wp2t, 512, bp2, nullptr, 0, 512, Xt, Mt, acc);

        // RZ = xi_bf @ [W_r|W_st]^T + bias_all   [512, 9216], K=640
        mgemm_k<0><<<dim3(72, 8), 256, 0, stream>>>(
            xi_bf, 640, Wt, 640, bias_all, RZ, 9216, 640, nullptr, nullptr, nullptr);

        // retrieval softmax + weighted hh sum -> sig_bf[:,128:]
        retrieval_k<<<(KOBS * HID) / 256, 256, 0, stream>>>(RZ, h_hat, idx_t, sig_bf);

        // h_tilde = tanh(sig_bf @ W_sig + b_sig)   [512,512], K=640
        mgemm_k<2><<<dim3(4, 8), 256, 0, stream>>>(
            sig_bf, 640, Wsigt, 640, b_sig, h_tilde, 512, 640, nullptr, nullptr, nullptr);

        // z softmax, state update + scatters
        update_k<<<(KOBS * HID) / 256, 256, 0, stream>>>(RZ, h_hat, idx_t, h_tilde, decay, h);
    }

    finalize_k<<<1, 1, 0, stream>>>(acc, (float*)d_out);
}